// Round 11
// baseline (61.184 us; speedup 1.0000x reference)
//
#include <hip/hip_runtime.h>
#include <math.h>

#define RES 96
#define NV 97
#define NV2 (NV * NV)                      // 9409
#define NCELLS (RES * RES * RES)           // 884736
#define NBLK 3456                          // 24*24*6 tiles of 4x4x16
#define MAX_DISP (2.0f / 96.0f / 4.0f)
#define NVT 425                            // 5*5*17 tile vertices

typedef float f32x4 __attribute__((ext_vector_type(4)));

__device__ __forceinline__ float grid_coord(int a) {
    // linspace(-0.5,0.5,97)[a] * 2  ==  a/48 - 1
    return fmaf((float)a, 1.0f / 48.0f, -1.0f);
}

__device__ __forceinline__ float fast_tanh(float x) {
    x = fminf(fmaxf(x, -15.f), 15.f);
    const float e = __expf(2.f * x);
    return (e - 1.f) * __builtin_amdgcn_rcpf(e + 1.f);
}

// One block = 4x4x16 cell tile, 256 threads (R8 structure — R9's 128-thread
// tile regressed). Changes this round:
//  * NO nontemporal hint on weights: nt evicted the 74MB stream from L3 and
//    forced a 44MB HBM refetch per replay (FETCH_SIZE evidence R6/R7).
//  * Two-pass weight staging: LDS 28.3KB -> 17.6KB (5 -> 8+ blocks/CU) for
//    latency hiding; all 1344 weight float4 loads issued up-front (pass B
//    parked in 12 VGPRs), so no extra memory latency on the critical path.
//  * launch_bounds(256,8) to keep VGPR<=64 (8 waves/SIMD).
// Partials to DISTINCT addresses + reduce kernel (same-address atomic tail
// serialized at the coherence point: 4x regression in R6/R7 — never again).
__global__ __launch_bounds__(256, 8) void flexi_fused(
    const float* __restrict__ sdf,
    const float* __restrict__ deform,
    const float* __restrict__ weights,
    float* __restrict__ out_vd,
    float* __restrict__ partial)
{
    __shared__ float  wlds[8 * 336];       // 8 segments x 336 floats = 10752B
    __shared__ float4 vs4[NVT];            // (x,y,z,sdf) per tile vertex, 6800B
    __shared__ float  sm[8];

    const int t = threadIdx.x;
    // chunked XCD swizzle: 8 XCDs x 432 contiguous tiles (bijective: 3456=8*432)
    const int bidx = (blockIdx.x & 7) * 432 + (blockIdx.x >> 3);
    const int bi = bidx / 144;             // i-tile (0..23)
    const int rb = bidx - bi * 144;
    const int bj = rb / 6;                 // j-tile (0..23)
    const int bk = rb - bj * 6;            // k-tile (0..5)

    // ---- issue ALL weight loads (both passes) + vertex loads up front ----
    const f32x4* w4 = reinterpret_cast<const f32x4*>(weights);
    f32x4 wa[3], wb[3];
    #pragma unroll
    for (int it = 0; it < 3; ++it) {
        // pass A: segments 0..7 (u = 0..671), pass B: segments 8..15
        const int uA = t + it * 256;
        const int uB = uA + 672;
        if (uA < 672) {
            const int sA = uA / 84, qA = uA - sA * 84;
            const int csA = (4 * bi + (sA >> 2)) * 9216 + (4 * bj + (sA & 3)) * 96 + 16 * bk;
            wa[it] = w4[(size_t)(csA >> 2) * 21 + qA];      // csA%4==0 -> exact
            const int sB = uB / 84, qB = uB - sB * 84;
            const int csB = (4 * bi + (sB >> 2)) * 9216 + (4 * bj + (sB & 3)) * 96 + 16 * bk;
            wb[it] = w4[(size_t)(csB >> 2) * 21 + qB];
        }
    }

    // ---- vertex gathers + tanh -> vs4 ----
    #pragma unroll
    for (int iv = 0; iv < 2; ++iv) {
        const int u = t + iv * 256;
        if (u < NVT) {
            const int a  = u / 85;             // 0..4
            const int r  = u - a * 85;
            const int b  = r / 17;             // 0..4
            const int cc = r - b * 17;         // 0..16
            const int gv = (4 * bi + a) * NV2 + (4 * bj + b) * NV + 16 * bk + cc;
            const float* dp = deform + (size_t)gv * 3;
            float4 vv;
            vv.x = grid_coord(4 * bi + a)   + MAX_DISP * fast_tanh(dp[0]);
            vv.y = grid_coord(4 * bj + b)   + MAX_DISP * fast_tanh(dp[1]);
            vv.z = grid_coord(16 * bk + cc) + MAX_DISP * fast_tanh(dp[2]);
            vv.w = sdf[gv];
            vs4[u] = vv;
        }
    }

    // ---- pass A weights -> LDS ----
    #pragma unroll
    for (int it = 0; it < 3; ++it) {
        const int u = t + it * 256;
        if (u < 672) reinterpret_cast<f32x4*>(wlds)[u] = wa[it];
    }
    __syncthreads();                           // vs4 + pass A ready

    // ---- per-cell fixed state: corners (all threads), weights (t<128) ----
    const int ti = t >> 6;
    const int tj = (t >> 4) & 3;
    const int tk = t & 15;
    const int vbase = ti * 85 + tj * 17 + tk;
    const int OFF[8] = {0, 85, 17, 102, 1, 86, 18, 103};   // reference corner order

    float s[8], x[8][3];
    #pragma unroll
    for (int k = 0; k < 8; ++k) {
        const float4 vv = vs4[vbase + OFF[k]];
        x[k][0] = vv.x; x[k][1] = vv.y; x[k][2] = vv.z;
        s[k] = vv.w;
    }

    float myw[21];                             // beta[0..11], alpha[12..19], gamma[20]
    const int seg = t >> 4;                    // 0..15
    if (t < 128) {
        const float* wrow = &wlds[seg * 336 + tk * 21];
        #pragma unroll
        for (int e = 0; e < 21; ++e) myw[e] = wrow[e];
    }
    __syncthreads();                           // pass A consumed

    // ---- pass B weights -> LDS (data already in regs, no latency) ----
    #pragma unroll
    for (int it = 0; it < 3; ++it) {
        const int u = t + it * 256;
        if (u < 672) reinterpret_cast<f32x4*>(wlds)[u] = wb[it];
    }
    __syncthreads();                           // pass B ready

    if (t >= 128) {
        const float* wrow = &wlds[(seg - 8) * 336 + tk * 21];
        #pragma unroll
        for (int e = 0; e < 21; ++e) myw[e] = wrow[e];
    }

    const int EA[12] = {0, 1, 4, 0, 2, 3, 6, 2, 2, 3, 7, 6};
    const int EB[12] = {1, 5, 5, 4, 3, 7, 7, 6, 0, 1, 5, 4};

    float p[12][3];
    bool  cross[12];
    float wsum = 0.f, vnum0 = 0.f, vnum1 = 0.f, vnum2 = 0.f;
    int   ncross = 0;
    #pragma unroll
    for (int e = 0; e < 12; ++e) {
        const int a = EA[e], b = EB[e];
        const float sa = s[a], sb = s[b];
        const bool cr = (sa > 0.f) != (sb > 0.f);
        cross[e] = cr;
        const float ta = myw[12 + a] * sb;
        const float tb = myw[12 + b] * sa;
        // den guard keeps p finite (w=0 masks its value, but 0*inf = NaN)
        const float den = cr ? (ta - tb) : 1.0f;
        const float inv = __builtin_amdgcn_rcpf(den);
        const float p0 = (ta * x[a][0] - tb * x[b][0]) * inv;
        const float p1 = (ta * x[a][1] - tb * x[b][1]) * inv;
        const float p2 = (ta * x[a][2] - tb * x[b][2]) * inv;
        p[e][0] = p0; p[e][1] = p1; p[e][2] = p2;
        const float w = cr ? myw[e] : 0.f;
        wsum  += w;
        vnum0 += w * p0;
        vnum1 += w * p1;
        vnum2 += w * p2;
        ncross += cr ? 1 : 0;
    }

    const bool surf = (ncross > 0);
    const float invden = __builtin_amdgcn_rcpf(surf ? wsum : 1.0f);
    float vd0 = vnum0 * invden;
    float vd1 = vnum1 * invden;
    float vd2 = vnum2 * invden;
    if (!surf) { vd0 = 0.f; vd1 = 0.f; vd2 = 0.f; }

    const int c = (4 * bi + ti) * 9216 + (4 * bj + tj) * 96 + 16 * bk + tk;
    out_vd[(size_t)c * 3 + 0] = vd0;
    out_vd[(size_t)c * 3 + 1] = vd1;
    out_vd[(size_t)c * 3 + 2] = vd2;

    float devsum = 0.f;
    #pragma unroll
    for (int e = 0; e < 12; ++e) {
        const float d0 = p[e][0] - vd0;
        const float d1 = p[e][1] - vd1;
        const float d2 = p[e][2] - vd2;
        const float nrm = __builtin_amdgcn_sqrtf(d0 * d0 + d1 * d1 + d2 * d2 + 1e-12f);
        devsum += cross[e] ? nrm : 0.f;
    }
    const float dev = devsum * __builtin_amdgcn_rcpf(fmaxf((float)ncross, 1.0f));
    float regc = surf ? dev * myw[20] : 0.f;
    float cnt  = surf ? 1.0f : 0.f;

    #pragma unroll
    for (int off = 32; off > 0; off >>= 1) {
        regc += __shfl_down(regc, off);
        cnt  += __shfl_down(cnt, off);
    }
    const int wid = t >> 6;
    if ((t & 63) == 0) { sm[wid] = regc; sm[4 + wid] = cnt; }
    __syncthreads();
    if (t == 0) {
        partial[bidx]        = sm[0] + sm[1] + sm[2] + sm[3];
        partial[NBLK + bidx] = sm[4] + sm[5] + sm[6] + sm[7];
    }
}

__global__ __launch_bounds__(1024) void flexi_reduce(
    const float* __restrict__ partial, float* __restrict__ reg_out)
{
    float a = 0.f, b = 0.f;
    for (int i = threadIdx.x; i < NBLK; i += 1024) {
        a += partial[i];
        b += partial[NBLK + i];
    }
    #pragma unroll
    for (int off = 32; off > 0; off >>= 1) {
        a += __shfl_down(a, off);
        b += __shfl_down(b, off);
    }
    __shared__ float sm[32];
    const int wid = threadIdx.x >> 6;      // 16 waves
    if ((threadIdx.x & 63) == 0) { sm[wid] = a; sm[16 + wid] = b; }
    __syncthreads();
    if (threadIdx.x == 0) {
        float num = 0.f, den = 0.f;
        #pragma unroll
        for (int i = 0; i < 16; ++i) { num += sm[i]; den += sm[16 + i]; }
        reg_out[0] = num / fmaxf(den, 1.0f);
    }
}

extern "C" void kernel_launch(void* const* d_in, const int* in_sizes, int n_in,
                              void* d_out, int out_size, void* d_ws, size_t ws_size,
                              hipStream_t stream)
{
    // inputs: verts(analytic), indices(analytic), sdf, deform, weights
    const float* sdf     = (const float*)d_in[2];
    const float* deform  = (const float*)d_in[3];
    const float* weights = (const float*)d_in[4];
    float* out     = (float*)d_out;
    float* partial = (float*)d_ws;     // 2*NBLK floats, all rewritten each call

    flexi_fused<<<NBLK, 256, 0, stream>>>(sdf, deform, weights, out, partial);
    flexi_reduce<<<1, 1024, 0, stream>>>(partial, out + (size_t)NCELLS * 3);
}

// Round 12
// 31.430 us; speedup vs baseline: 1.9467x; 1.9467x over previous
//
#include <hip/hip_runtime.h>
#include <math.h>

#define RES 96
#define NV 97
#define NV2 (NV * NV)                      // 9409
#define NCELLS (RES * RES * RES)           // 884736
#define NBLK 3456                          // 24*24*6 tiles of 4x4x16
#define MAX_DISP (2.0f / 96.0f / 4.0f)
#define NVT 425                            // 5*5*17 tile vertices

typedef float f32x4 __attribute__((ext_vector_type(4)));

__device__ __forceinline__ float grid_coord(int a) {
    // linspace(-0.5,0.5,97)[a] * 2  ==  a/48 - 1
    return fmaf((float)a, 1.0f / 48.0f, -1.0f);
}

__device__ __forceinline__ float fast_tanh(float x) {
    x = fminf(fmaxf(x, -15.f), 15.f);
    const float e = __expf(2.f * x);
    return (e - 1.f) * __builtin_amdgcn_rcpf(e + 1.f);
}

// R9 structure (best: 35.1us), single change: NO nontemporal hint on the
// weights load. Theory: nt marked the 74MB weights stream evict-first in
// L2/L3, causing the steady-state 44MB/replay HBM refetch seen in R6/R7
// FETCH_SIZE. Plain loads let the L3 (256MB) retain all inputs (~100MB).
// Hard-won constraints: no same-address atomic tails (R6/R7: +110us), no
// forced occupancy bounds beyond 3 (R11: VGPR=32 -> 145MB scratch spill),
// 256-thread 4x4x16 tile (R10's 128-thread tile regressed).
__global__ __launch_bounds__(256, 3) void flexi_fused(
    const float* __restrict__ sdf,
    const float* __restrict__ deform,
    const float* __restrict__ weights,
    float* __restrict__ out_vd,
    float* __restrict__ partial)
{
    __shared__ float  wlds[16 * 336];      // 16 k-runs x 336 floats
    __shared__ float4 vs4[NVT];            // (x,y,z,sdf) per tile vertex
    __shared__ float  sm[8];

    const int t = threadIdx.x;
    // chunked XCD swizzle: 8 XCDs x 432 contiguous tiles (bijective: 3456=8*432)
    const int bidx = (blockIdx.x & 7) * 432 + (blockIdx.x >> 3);
    const int bi = bidx / 144;             // i-tile (0..23)
    const int rb = bidx - bi * 144;
    const int bj = rb / 6;                 // j-tile (0..23)
    const int bk = rb - bj * 6;            // k-tile (0..5)

    // ---- stage weights: 16 segments of 336 contiguous, 16B-aligned floats ----
    {
        const f32x4* w4 = reinterpret_cast<const f32x4*>(weights);
        #pragma unroll
        for (int it = 0; it < 6; ++it) {
            const int u = t + it * 256;
            if (u < 16 * 84) {
                const int s = u / 84;
                const int q = u - s * 84;
                const int cs = (4 * bi + (s >> 2)) * 9216 + (4 * bj + (s & 3)) * 96 + 16 * bk;
                const f32x4 v = w4[(size_t)(cs >> 2) * 21 + q];   // cs%4==0 -> exact
                float* dst = &wlds[s * 336 + q * 4];
                dst[0] = v.x; dst[1] = v.y; dst[2] = v.z; dst[3] = v.w;
            }
        }
    }

    // ---- stage tile vertices: (deformed pos, sdf) as float4 ----
    #pragma unroll
    for (int it = 0; it < 2; ++it) {
        const int u = t + it * 256;
        if (u < NVT) {
            const int a  = u / 85;             // 0..4
            const int r  = u - a * 85;
            const int b  = r / 17;             // 0..4
            const int cc = r - b * 17;         // 0..16
            const int gv = (4 * bi + a) * NV2 + (4 * bj + b) * NV + 16 * bk + cc;
            const float* dp = deform + (size_t)gv * 3;
            float4 vv;
            vv.x = grid_coord(4 * bi + a)   + MAX_DISP * fast_tanh(dp[0]);
            vv.y = grid_coord(4 * bj + b)   + MAX_DISP * fast_tanh(dp[1]);
            vv.z = grid_coord(16 * bk + cc) + MAX_DISP * fast_tanh(dp[2]);
            vv.w = sdf[gv];
            vs4[u] = vv;
        }
    }
    __syncthreads();

    // ---- per-cell compute ----
    const int ti = t >> 6;
    const int tj = (t >> 4) & 3;
    const int tk = t & 15;
    const int vbase = ti * 85 + tj * 17 + tk;
    const int OFF[8] = {0, 85, 17, 102, 1, 86, 18, 103};   // reference corner order

    float s[8], x[8][3];
    #pragma unroll
    for (int k = 0; k < 8; ++k) {
        const float4 vv = vs4[vbase + OFF[k]];
        x[k][0] = vv.x; x[k][1] = vv.y; x[k][2] = vv.z;
        s[k] = vv.w;
    }

    const float* wrow = &wlds[t * 21];     // stride 21: odd -> conflict-free
    float beta[12], alpha[8];
    #pragma unroll
    for (int e = 0; e < 12; ++e) beta[e] = wrow[e];
    #pragma unroll
    for (int k = 0; k < 8; ++k) alpha[k] = wrow[12 + k];
    const float gamma = wrow[20];

    const int EA[12] = {0, 1, 4, 0, 2, 3, 6, 2, 2, 3, 7, 6};
    const int EB[12] = {1, 5, 5, 4, 3, 7, 7, 6, 0, 1, 5, 4};

    float p[12][3];
    bool  cross[12];
    float wsum = 0.f, vnum0 = 0.f, vnum1 = 0.f, vnum2 = 0.f;
    int   ncross = 0;
    #pragma unroll
    for (int e = 0; e < 12; ++e) {
        const int a = EA[e], b = EB[e];
        const float sa = s[a], sb = s[b];
        const bool cr = (sa > 0.f) != (sb > 0.f);
        cross[e] = cr;
        const float ta = alpha[a] * sb;
        const float tb = alpha[b] * sa;
        // den guard keeps p finite (w=0 masks its value, but 0*inf = NaN)
        const float den = cr ? (ta - tb) : 1.0f;
        const float inv = __builtin_amdgcn_rcpf(den);
        const float p0 = (ta * x[a][0] - tb * x[b][0]) * inv;
        const float p1 = (ta * x[a][1] - tb * x[b][1]) * inv;
        const float p2 = (ta * x[a][2] - tb * x[b][2]) * inv;
        p[e][0] = p0; p[e][1] = p1; p[e][2] = p2;
        const float w = cr ? beta[e] : 0.f;
        wsum  += w;
        vnum0 += w * p0;
        vnum1 += w * p1;
        vnum2 += w * p2;
        ncross += cr ? 1 : 0;
    }

    const bool surf = (ncross > 0);
    const float invden = __builtin_amdgcn_rcpf(surf ? wsum : 1.0f);
    float vd0 = vnum0 * invden;
    float vd1 = vnum1 * invden;
    float vd2 = vnum2 * invden;
    if (!surf) { vd0 = 0.f; vd1 = 0.f; vd2 = 0.f; }

    const int c = (4 * bi + ti) * 9216 + (4 * bj + tj) * 96 + 16 * bk + tk;
    out_vd[(size_t)c * 3 + 0] = vd0;
    out_vd[(size_t)c * 3 + 1] = vd1;
    out_vd[(size_t)c * 3 + 2] = vd2;

    float devsum = 0.f;
    #pragma unroll
    for (int e = 0; e < 12; ++e) {
        const float d0 = p[e][0] - vd0;
        const float d1 = p[e][1] - vd1;
        const float d2 = p[e][2] - vd2;
        const float nrm = __builtin_amdgcn_sqrtf(d0 * d0 + d1 * d1 + d2 * d2 + 1e-12f);
        devsum += cross[e] ? nrm : 0.f;
    }
    const float dev = devsum * __builtin_amdgcn_rcpf(fmaxf((float)ncross, 1.0f));
    float regc = surf ? dev * gamma : 0.f;
    float cnt  = surf ? 1.0f : 0.f;

    #pragma unroll
    for (int off = 32; off > 0; off >>= 1) {
        regc += __shfl_down(regc, off);
        cnt  += __shfl_down(cnt, off);
    }
    const int wid = t >> 6;
    if ((t & 63) == 0) { sm[wid] = regc; sm[4 + wid] = cnt; }
    __syncthreads();
    if (t == 0) {
        partial[bidx]        = sm[0] + sm[1] + sm[2] + sm[3];
        partial[NBLK + bidx] = sm[4] + sm[5] + sm[6] + sm[7];
    }
}

__global__ __launch_bounds__(1024) void flexi_reduce(
    const float* __restrict__ partial, float* __restrict__ reg_out)
{
    float a = 0.f, b = 0.f;
    for (int i = threadIdx.x; i < NBLK; i += 1024) {
        a += partial[i];
        b += partial[NBLK + i];
    }
    #pragma unroll
    for (int off = 32; off > 0; off >>= 1) {
        a += __shfl_down(a, off);
        b += __shfl_down(b, off);
    }
    __shared__ float sm[32];
    const int wid = threadIdx.x >> 6;      // 16 waves
    if ((threadIdx.x & 63) == 0) { sm[wid] = a; sm[16 + wid] = b; }
    __syncthreads();
    if (threadIdx.x == 0) {
        float num = 0.f, den = 0.f;
        #pragma unroll
        for (int i = 0; i < 16; ++i) { num += sm[i]; den += sm[16 + i]; }
        reg_out[0] = num / fmaxf(den, 1.0f);
    }
}

extern "C" void kernel_launch(void* const* d_in, const int* in_sizes, int n_in,
                              void* d_out, int out_size, void* d_ws, size_t ws_size,
                              hipStream_t stream)
{
    // inputs: verts(analytic), indices(analytic), sdf, deform, weights
    const float* sdf     = (const float*)d_in[2];
    const float* deform  = (const float*)d_in[3];
    const float* weights = (const float*)d_in[4];
    float* out     = (float*)d_out;
    float* partial = (float*)d_ws;     // 2*NBLK floats, all rewritten each call

    flexi_fused<<<NBLK, 256, 0, stream>>>(sdf, deform, weights, out, partial);
    flexi_reduce<<<1, 1024, 0, stream>>>(partial, out + (size_t)NCELLS * 3);
}

// Round 13
// 25.513 us; speedup vs baseline: 2.3981x; 1.2319x over previous
//
#include <hip/hip_runtime.h>
#include <math.h>

#define RES 96
#define NV 97
#define NV2 (NV * NV)                      // 9409
#define NCELLS (RES * RES * RES)           // 884736
#define NBLK 3456                          // 24*24*6 tiles of 4x4x16
#define MAX_DISP (2.0f / 96.0f / 4.0f)
#define NVT 425                            // 5*5*17 tile vertices

typedef float f32x4 __attribute__((ext_vector_type(4)));

__device__ __forceinline__ float grid_coord(int a) {
    // linspace(-0.5,0.5,97)[a] * 2  ==  a/48 - 1
    return fmaf((float)a, 1.0f / 48.0f, -1.0f);
}

__device__ __forceinline__ float fast_tanh(float x) {
    x = fminf(fmaxf(x, -15.f), 15.f);
    const float e = __expf(2.f * x);
    return (e - 1.f) * __builtin_amdgcn_rcpf(e + 1.f);
}

// R12 structure, one structural change: NO weights LDS tile. Each thread
// loads its own 21-float row direct global->regs (issued first; a wave pulls
// a contiguous 5.3KB window -> L1/L2 friendly). LDS drops 28.6 -> 7.2KB so
// residency goes 5 -> 8 blocks/CU (32/32 wave slots) — the R12 kernel was
// ~75% latency-stalled (500 VALU/thread ~ 5.6us vs 25us observed).
// Hard-won constraints: no nt hints (L3 refetch, R12), no same-address
// atomic tails (R6/R7), no forced VGPR bounds (R11 spill), 256-thread
// 4x4x16 tile (R10 regressed).
__global__ __launch_bounds__(256) void flexi_fused(
    const float* __restrict__ sdf,
    const float* __restrict__ deform,
    const float* __restrict__ weights,
    float* __restrict__ out_vd,
    float* __restrict__ partial)
{
    __shared__ float4 vs4[NVT];            // (x,y,z,sdf) per tile vertex, 6.8KB
    __shared__ float  sm[8];

    const int t = threadIdx.x;
    // chunked XCD swizzle: 8 XCDs x 432 contiguous tiles (bijective: 3456=8*432)
    const int bidx = (blockIdx.x & 7) * 432 + (blockIdx.x >> 3);
    const int bi = bidx / 144;             // i-tile (0..23)
    const int rb = bidx - bi * 144;
    const int bj = rb / 6;                 // j-tile (0..23)
    const int bk = rb - bj * 6;            // k-tile (0..5)

    // ---- cell id + weights row loads issued FIRST (latency hides under tanh) ----
    const int ti = t >> 6;
    const int tj = (t >> 4) & 3;
    const int tk = t & 15;
    const int c = (4 * bi + ti) * 9216 + (4 * bj + tj) * 96 + 16 * bk + tk;
    const float* wrow = weights + (size_t)c * 21;
    float myw[21];                         // beta[0..11], alpha[12..19], gamma[20]
    #pragma unroll
    for (int e = 0; e < 21; ++e) myw[e] = wrow[e];

    // ---- stage tile vertices: (deformed pos, sdf) as float4 ----
    #pragma unroll
    for (int it = 0; it < 2; ++it) {
        const int u = t + it * 256;
        if (u < NVT) {
            const int a  = u / 85;             // 0..4
            const int r  = u - a * 85;
            const int b  = r / 17;             // 0..4
            const int cc = r - b * 17;         // 0..16
            const int gv = (4 * bi + a) * NV2 + (4 * bj + b) * NV + 16 * bk + cc;
            const float* dp = deform + (size_t)gv * 3;
            float4 vv;
            vv.x = grid_coord(4 * bi + a)   + MAX_DISP * fast_tanh(dp[0]);
            vv.y = grid_coord(4 * bj + b)   + MAX_DISP * fast_tanh(dp[1]);
            vv.z = grid_coord(16 * bk + cc) + MAX_DISP * fast_tanh(dp[2]);
            vv.w = sdf[gv];
            vs4[u] = vv;
        }
    }
    __syncthreads();

    // ---- per-cell compute ----
    const int vbase = ti * 85 + tj * 17 + tk;
    const int OFF[8] = {0, 85, 17, 102, 1, 86, 18, 103};   // reference corner order

    float s[8], x[8][3];
    #pragma unroll
    for (int k = 0; k < 8; ++k) {
        const float4 vv = vs4[vbase + OFF[k]];
        x[k][0] = vv.x; x[k][1] = vv.y; x[k][2] = vv.z;
        s[k] = vv.w;
    }

    const int EA[12] = {0, 1, 4, 0, 2, 3, 6, 2, 2, 3, 7, 6};
    const int EB[12] = {1, 5, 5, 4, 3, 7, 7, 6, 0, 1, 5, 4};

    float p[12][3];
    bool  cross[12];
    float wsum = 0.f, vnum0 = 0.f, vnum1 = 0.f, vnum2 = 0.f;
    int   ncross = 0;
    #pragma unroll
    for (int e = 0; e < 12; ++e) {
        const int a = EA[e], b = EB[e];
        const float sa = s[a], sb = s[b];
        const bool cr = (sa > 0.f) != (sb > 0.f);
        cross[e] = cr;
        const float ta = myw[12 + a] * sb;
        const float tb = myw[12 + b] * sa;
        // den guard keeps p finite (w=0 masks its value, but 0*inf = NaN)
        const float den = cr ? (ta - tb) : 1.0f;
        const float inv = __builtin_amdgcn_rcpf(den);
        const float p0 = (ta * x[a][0] - tb * x[b][0]) * inv;
        const float p1 = (ta * x[a][1] - tb * x[b][1]) * inv;
        const float p2 = (ta * x[a][2] - tb * x[b][2]) * inv;
        p[e][0] = p0; p[e][1] = p1; p[e][2] = p2;
        const float w = cr ? myw[e] : 0.f;
        wsum  += w;
        vnum0 += w * p0;
        vnum1 += w * p1;
        vnum2 += w * p2;
        ncross += cr ? 1 : 0;
    }

    const bool surf = (ncross > 0);
    const float invden = __builtin_amdgcn_rcpf(surf ? wsum : 1.0f);
    float vd0 = vnum0 * invden;
    float vd1 = vnum1 * invden;
    float vd2 = vnum2 * invden;
    if (!surf) { vd0 = 0.f; vd1 = 0.f; vd2 = 0.f; }

    out_vd[(size_t)c * 3 + 0] = vd0;
    out_vd[(size_t)c * 3 + 1] = vd1;
    out_vd[(size_t)c * 3 + 2] = vd2;

    float devsum = 0.f;
    #pragma unroll
    for (int e = 0; e < 12; ++e) {
        const float d0 = p[e][0] - vd0;
        const float d1 = p[e][1] - vd1;
        const float d2 = p[e][2] - vd2;
        const float nrm = __builtin_amdgcn_sqrtf(d0 * d0 + d1 * d1 + d2 * d2 + 1e-12f);
        devsum += cross[e] ? nrm : 0.f;
    }
    const float dev = devsum * __builtin_amdgcn_rcpf(fmaxf((float)ncross, 1.0f));
    float regc = surf ? dev * myw[20] : 0.f;
    float cnt  = surf ? 1.0f : 0.f;

    #pragma unroll
    for (int off = 32; off > 0; off >>= 1) {
        regc += __shfl_down(regc, off);
        cnt  += __shfl_down(cnt, off);
    }
    const int wid = t >> 6;
    if ((t & 63) == 0) { sm[wid] = regc; sm[4 + wid] = cnt; }
    __syncthreads();
    if (t == 0) {
        partial[bidx]        = sm[0] + sm[1] + sm[2] + sm[3];
        partial[NBLK + bidx] = sm[4] + sm[5] + sm[6] + sm[7];
    }
}

__global__ __launch_bounds__(1024) void flexi_reduce(
    const float* __restrict__ partial, float* __restrict__ reg_out)
{
    float a = 0.f, b = 0.f;
    for (int i = threadIdx.x; i < NBLK; i += 1024) {
        a += partial[i];
        b += partial[NBLK + i];
    }
    #pragma unroll
    for (int off = 32; off > 0; off >>= 1) {
        a += __shfl_down(a, off);
        b += __shfl_down(b, off);
    }
    __shared__ float sm[32];
    const int wid = threadIdx.x >> 6;      // 16 waves
    if ((threadIdx.x & 63) == 0) { sm[wid] = a; sm[16 + wid] = b; }
    __syncthreads();
    if (threadIdx.x == 0) {
        float num = 0.f, den = 0.f;
        #pragma unroll
        for (int i = 0; i < 16; ++i) { num += sm[i]; den += sm[16 + i]; }
        reg_out[0] = num / fmaxf(den, 1.0f);
    }
}

extern "C" void kernel_launch(void* const* d_in, const int* in_sizes, int n_in,
                              void* d_out, int out_size, void* d_ws, size_t ws_size,
                              hipStream_t stream)
{
    // inputs: verts(analytic), indices(analytic), sdf, deform, weights
    const float* sdf     = (const float*)d_in[2];
    const float* deform  = (const float*)d_in[3];
    const float* weights = (const float*)d_in[4];
    float* out     = (float*)d_out;
    float* partial = (float*)d_ws;     // 2*NBLK floats, all rewritten each call

    flexi_fused<<<NBLK, 256, 0, stream>>>(sdf, deform, weights, out, partial);
    flexi_reduce<<<1, 1024, 0, stream>>>(partial, out + (size_t)NCELLS * 3);
}